// Round 8
// baseline (390.432 us; speedup 1.0000x reference)
//
#include <hip/hip_runtime.h>
#include <math.h>

#define HID 128
#define NEXP 8
#define NGRAPH 64
#define EPC 16384      // edges per chunk (pass A blocks)
#define MAXB 512       // max coarse buckets (n <= 131072)
#define NREP 8         // pool replicas (atomic-contention spreading)

__device__ inline unsigned short f2bf(float f) {
    unsigned u = __float_as_uint(f);
    u += 0x7FFF + ((u >> 16) & 1);          // RNE
    return (unsigned short)(u >> 16);
}
__device__ inline float bf2f(unsigned short u) {
    return __uint_as_float(((unsigned)u) << 16);
}

// ---------------- init: pool/pcnt/cnt/bcnt zero, C = W2@Wlin, bb2 = b2@Wlin ----
__global__ void k_init0(float* __restrict__ pool, float* __restrict__ pcnt,
                        const float* __restrict__ W2, const float* __restrict__ Wlin,
                        const float* __restrict__ b2, float* __restrict__ C,
                        float* __restrict__ bb2, int* __restrict__ cnt,
                        int* __restrict__ bcnt, int n) {
    int i = blockIdx.x * 256 + threadIdx.x;
    if (i < n) cnt[i] = 0;
    if (i < MAXB) bcnt[i] = 0;
    if (i < NREP * NGRAPH * NEXP) pool[i] = 0.0f;
    if (i < NREP * NGRAPH) pcnt[i] = 0.0f;
    if (i >= n) {
        int ci = i - n;
        if (ci < HID * NEXP) {        // C[k][j] = sum_m W2[k][m]*Wlin[m][j]
            int k = ci >> 3, j = ci & 7;
            float s = 0.0f;
            for (int m = 0; m < HID; m++) s += W2[k * HID + m] * Wlin[m * NEXP + j];
            C[ci] = s;
        } else if (ci - HID * NEXP < NEXP) {   // bb2[j] = sum_m b2[m]*Wlin[m][j]
            int bi = ci - HID * NEXP;
            float s = 0.0f;
            for (int m = 0; m < HID; m++) s += b2[m] * Wlin[m * NEXP + bi];
            bb2[bi] = s;
        }
    }
}

// ---------------- pass 0: per-chunk coarse histogram + per-node degree ---------
// runcnt layout [c][b] (coalesced across threads everywhere it's walked).
__global__ void k_hist(const int* __restrict__ dst, int* __restrict__ runcnt,
                       int* __restrict__ bcnt, int* __restrict__ cnt,
                       int e, int nbuck) {
    __shared__ int h[MAXB];
    int c = blockIdx.x, t = threadIdx.x;
    for (int b = t; b < nbuck; b += 256) h[b] = 0;
    __syncthreads();
    int start = c * EPC;
    int end = start + EPC < e ? start + EPC : e;
    for (int i = start + t; i < end; i += 256) {
        int d = dst[i];
        atomicAdd(&h[d >> 8], 1);
        atomicAdd(&cnt[d], 1);          // per-node degree (low contention)
    }
    __syncthreads();
    for (int b = t; b < nbuck; b += 256) {
        runcnt[c * nbuck + b] = h[b];
        if (h[b]) atomicAdd(&bcnt[b], h[b]);
    }
}

// ---------------- bucket scan (<=512 buckets, 1 small block) -------------------
__global__ void k_cscan(const int* __restrict__ bcnt, int* __restrict__ boff,
                        int e, int nbuck) {
    __shared__ int s[512];
    int t = threadIdx.x;
    int v = (t < nbuck) ? bcnt[t] : 0;
    s[t] = v;
    __syncthreads();
    for (int d = 1; d < 512; d <<= 1) {
        int x = (t >= d) ? s[t - d] : 0;
        __syncthreads();
        s[t] += x;
        __syncthreads();
    }
    if (t < nbuck) boff[t] = s[t] - v;
    if (t == 0) boff[nbuck] = e;
}

// ---------------- parallel per-bucket chunk prefix (coalesced [c][b]) ----------
__global__ void k_off(int* __restrict__ runcnt, const int* __restrict__ boff,
                      int ch, int nbuck) {
    int b = blockIdx.x * 256 + threadIdx.x;
    if (b >= nbuck) return;
    int run = boff[b];
    for (int c0 = 0; c0 < ch; c0 += 8) {
        int v[8];
#pragma unroll
        for (int j = 0; j < 8; j++)
            v[j] = (c0 + j < ch) ? runcnt[(c0 + j) * nbuck + b] : 0;
#pragma unroll
        for (int j = 0; j < 8; j++) {
            if (c0 + j < ch) runcnt[(c0 + j) * nbuck + b] = run;
            run += v[j];
        }
    }
}

// ---------------- per-node: dinv + scaled 4-dim features -----------------------
__global__ void k_dx(const float* __restrict__ an, const float* __restrict__ pos,
                     const int* __restrict__ cnt, float* __restrict__ dinv,
                     float4* __restrict__ xs, int n) {
    int i = blockIdx.x * 256 + threadIdx.x;
    if (i >= n) return;
    float di = rsqrtf((float)cnt[i] + 1.0f);   // +1 = self-loop
    dinv[i] = di;
    xs[i] = make_float4(an[i] * di, pos[3 * i] * di,
                        pos[3 * i + 1] * di, pos[3 * i + 2] * di);
}

// ---------------- pass A: bin edges into bucket-contiguous order ---------------
__global__ void k_binA(const int* __restrict__ src, const int* __restrict__ dst,
                       const int* __restrict__ runcnt, unsigned* __restrict__ binned,
                       int e, int nbuck) {
    __shared__ int cur[MAXB];
    int c = blockIdx.x, t = threadIdx.x;
    for (int b = t; b < nbuck; b += 256) cur[b] = runcnt[c * nbuck + b];
    __syncthreads();
    int start = c * EPC;
    int end = start + EPC < e ? start + EPC : e;
    for (int i = start + t; i < end; i += 256) {
        int d = dst[i];
        int p = atomicAdd(&cur[d >> 8], 1);
        binned[p] = ((unsigned)(d & 255) << 24) | (unsigned)src[i];
    }
}

// ---------------- layer-1 gather: bucket-block, LDS fp32 accumulate ------------
// stride 5 floats per node slot -> banks spread for random fine ids.
__global__ void k_gx2(const unsigned* __restrict__ binned, const int* __restrict__ boff,
                      const float4* __restrict__ xs, float4* __restrict__ agg4, int n) {
    __shared__ float acc[256 * 5];
    int b = blockIdx.x, t = threadIdx.x;
#pragma unroll
    for (int j = 0; j < 5; j++) acc[j * 256 + t] = 0.0f;   // (re-indexed zero)
    __syncthreads();
    int s0 = boff[b], s1 = boff[b + 1];
    for (int k = s0 + t; k < s1; k += 256) {
        unsigned u = binned[k];
        int d = u >> 24;
        float4 v = xs[u & 0xFFFFFF];
        atomicAdd(&acc[d * 5 + 0], v.x);
        atomicAdd(&acc[d * 5 + 1], v.y);
        atomicAdd(&acc[d * 5 + 2], v.z);
        atomicAdd(&acc[d * 5 + 3], v.w);
    }
    __syncthreads();
    int node = (b << 8) + t;
    if (node < n) {
        float4 self = xs[node];
        agg4[node] = make_float4(self.x + acc[t * 5 + 0], self.y + acc[t * 5 + 1],
                                 self.z + acc[t * 5 + 2], self.w + acc[t * 5 + 3]);
    }
}

// ---------------- fused layer-1 dense + z projection ---------------------------
// x1_i = relu(dinv*(agg4@W1)+b1) in wave registers; z_i = (x1_i@C)*dinv, bf16[8]
__global__ void k_hz(const float4* __restrict__ agg4, const float* __restrict__ W1,
                     const float* __restrict__ b1, const float* __restrict__ C,
                     const float* __restrict__ dinv, unsigned short* __restrict__ z,
                     int n) {
    __shared__ float xh[4][HID];
    int w = threadIdx.x >> 6;
    int i = blockIdx.x * 4 + w;
    int p = threadIdx.x & 63;
    int ic = i < n ? i : n - 1;
    const float2* W1v = (const float2*)W1;
    float2 w0 = W1v[0 * 64 + p], w1 = W1v[1 * 64 + p],
           w2 = W1v[2 * 64 + p], w3 = W1v[3 * 64 + p];
    float4 a = agg4[ic];
    float di = dinv[ic];
    float2 bb = ((const float2*)b1)[p];
    float h0 = fmaxf(di * (a.x * w0.x + a.y * w1.x + a.z * w2.x + a.w * w3.x) + bb.x, 0.0f);
    float h1 = fmaxf(di * (a.x * w0.y + a.y * w1.y + a.z * w2.y + a.w * w3.y) + bb.y, 0.0f);
    xh[w][2 * p]     = h0;
    xh[w][2 * p + 1] = h1;
    __syncthreads();
    int seg = p >> 3, j = p & 7;
    float val = 0.0f;
#pragma unroll
    for (int q = 0; q < 16; q++) {
        int c = seg * 16 + q;
        val += xh[w][c] * C[c * NEXP + j];
    }
#pragma unroll
    for (int m = 8; m < 64; m <<= 1)
        val += __shfl_xor(val, m, 64);
    if (p < 8 && i < n) z[(size_t)i * NEXP + p] = f2bf(val * di);
}

// ---------------- layer-2 gather + pooling: bucket-block LDS accumulate --------
// zacc stride 9 floats per node -> banks spread; then per-graph LDS pool + flush.
__global__ void k_gz2(const unsigned* __restrict__ binned, const int* __restrict__ boff,
                      const unsigned short* __restrict__ z, const float* __restrict__ dinv,
                      const int* __restrict__ batch, float* __restrict__ pool,
                      float* __restrict__ pcnt, int n) {
    __shared__ float zacc[256 * 9];
    __shared__ float gsum[NGRAPH * NEXP];
    __shared__ float gcnt[NGRAPH];
    __shared__ int touched[NGRAPH];
    int b = blockIdx.x, t = threadIdx.x;
#pragma unroll
    for (int j = 0; j < 9; j++) zacc[j * 256 + t] = 0.0f;
    for (int idx = t; idx < NGRAPH * NEXP; idx += 256) gsum[idx] = 0.0f;
    if (t < NGRAPH) { gcnt[t] = 0.0f; touched[t] = 0; }
    __syncthreads();

    int s0 = boff[b], s1 = boff[b + 1];
    for (int k = s0 + t; k < s1; k += 256) {
        unsigned u = binned[k];
        int d = u >> 24;
        const uint2 zr = *(const uint2*)(z + (size_t)(u & 0xFFFFFF) * NEXP);
        float* ap = &zacc[d * 9];
        atomicAdd(ap + 0, bf2f((unsigned short)(zr.x & 0xFFFF)));
        atomicAdd(ap + 1, bf2f((unsigned short)(zr.x >> 16)));
        atomicAdd(ap + 2, bf2f((unsigned short)((zr.y) & 0xFFFF)));
        atomicAdd(ap + 3, bf2f((unsigned short)(zr.y >> 16)));
        const uint2 zr2 = *(const uint2*)(z + (size_t)(u & 0xFFFFFF) * NEXP + 4);
        atomicAdd(ap + 4, bf2f((unsigned short)(zr2.x & 0xFFFF)));
        atomicAdd(ap + 5, bf2f((unsigned short)(zr2.x >> 16)));
        atomicAdd(ap + 6, bf2f((unsigned short)(zr2.y & 0xFFFF)));
        atomicAdd(ap + 7, bf2f((unsigned short)(zr2.y >> 16)));
    }
    __syncthreads();

    int node = (b << 8) + t;
    if (node < n) {
        float di = dinv[node];
        int g = batch[node];
        touched[g] = 1;
        const unsigned short* zs = z + (size_t)node * NEXP;
#pragma unroll
        for (int j = 0; j < NEXP; j++) {
            float v = di * (zacc[t * 9 + j] + bf2f(zs[j]));
            atomicAdd(&gsum[g * NEXP + j], v);
        }
        atomicAdd(&gcnt[g], 1.0f);
    }
    __syncthreads();

    float* rp  = pool + (size_t)(b & (NREP - 1)) * NGRAPH * NEXP;
    float* rpc = pcnt + (size_t)(b & (NREP - 1)) * NGRAPH;
    for (int idx = t; idx < NGRAPH * NEXP; idx += 256) {
        if (touched[idx >> 3]) atomicAdd(&rp[idx], gsum[idx]);
    }
    if (t < NGRAPH && touched[t]) atomicAdd(&rpc[t], gcnt[t]);
}

// ---------------- replica-sum + mean + (blin + b2@Wlin) + log_softmax ----------
__global__ void k_lsm(const float* __restrict__ pool, const float* __restrict__ pcnt,
                      const float* __restrict__ blin, const float* __restrict__ bb2,
                      float* __restrict__ out) {
    int g = threadIdx.x;
    if (g >= NGRAPH) return;
    float p[NEXP];
#pragma unroll
    for (int k = 0; k < NEXP; k++) p[k] = 0.0f;
    float cg = 0.0f;
#pragma unroll
    for (int rr = 0; rr < NREP; rr++) {
#pragma unroll
        for (int k = 0; k < NEXP; k++) p[k] += pool[rr * NGRAPH * NEXP + g * NEXP + k];
        cg += pcnt[rr * NGRAPH + g];
    }
    float inv = 1.0f / fmaxf(cg, 1.0f);
    float v[NEXP], m = -1e30f;
#pragma unroll
    for (int k = 0; k < NEXP; k++) {
        v[k] = p[k] * inv + blin[k] + bb2[k];
        m = fmaxf(m, v[k]);
    }
    float s = 0.0f;
#pragma unroll
    for (int k = 0; k < NEXP; k++) s += expf(v[k] - m);
    float ls = logf(s);
#pragma unroll
    for (int k = 0; k < NEXP; k++) out[g * NEXP + k] = v[k] - m - ls;
}

extern "C" void kernel_launch(void* const* d_in, const int* in_sizes, int n_in,
                              void* d_out, int out_size, void* d_ws, size_t ws_size,
                              hipStream_t stream) {
    const float* an   = (const float*)d_in[0];
    const float* pos  = (const float*)d_in[1];
    const int*   ei   = (const int*)d_in[2];     // [2, E] flat (int32 view)
    const int*   batch= (const int*)d_in[3];
    const float* W1   = (const float*)d_in[4];
    const float* b1   = (const float*)d_in[5];
    const float* W2   = (const float*)d_in[6];
    const float* b2   = (const float*)d_in[7];
    const float* Wlin = (const float*)d_in[8];
    const float* blin = (const float*)d_in[9];
    float* out = (float*)d_out;

    const int n = in_sizes[0];
    const int e = in_sizes[2] / 2;
    const int* src = ei;
    const int* dst = ei + e;

    const int nbuck = (n + 255) >> 8;            // coarse buckets (<= MAXB)
    const int ch    = (e + EPC - 1) / EPC;       // chunks

    // workspace layout (16B-aligned buffers first)
    char* p = (char*)d_ws;
    float4* xs    = (float4*)p;       p += sizeof(float4) * (size_t)n;
    float4* agg4  = (float4*)p;       p += sizeof(float4) * (size_t)n;
    unsigned short* z = (unsigned short*)p;  p += sizeof(short) * (size_t)n * NEXP;
    float* C      = (float*)p;        p += sizeof(float) * HID * NEXP;
    float* bb2    = (float*)p;        p += sizeof(float) * NEXP;
    float* dinv   = (float*)p;        p += sizeof(float) * (size_t)n;
    float* pool   = (float*)p;        p += sizeof(float) * NREP * NGRAPH * NEXP;
    float* pcnt   = (float*)p;        p += sizeof(float) * NREP * NGRAPH;
    int*   cnt    = (int*)p;          p += sizeof(int) * (size_t)n;
    int*   bcnt   = (int*)p;          p += sizeof(int) * (MAXB + 1);
    int*   boff   = (int*)p;          p += sizeof(int) * (MAXB + 1);
    int*   runcnt = (int*)p;          p += sizeof(int) * (size_t)ch * nbuck;
    unsigned* binned = (unsigned*)p;  p += sizeof(unsigned) * (size_t)e;

    // init + CSR-lite build (coarse sort only)
    const int initN = n + HID * NEXP + NEXP;
    k_init0<<<(initN + 255) / 256, 256, 0, stream>>>(pool, pcnt, W2, Wlin, b2, C,
                                                     bb2, cnt, bcnt, n);
    k_hist<<<ch, 256, 0, stream>>>(dst, runcnt, bcnt, cnt, e, nbuck);
    k_cscan<<<1, 512, 0, stream>>>(bcnt, boff, e, nbuck);
    k_off<<<(nbuck + 255) / 256, 256, 0, stream>>>(runcnt, boff, ch, nbuck);
    k_dx<<<(n + 255) / 256, 256, 0, stream>>>(an, pos, cnt, dinv, xs, n);
    k_binA<<<ch, 256, 0, stream>>>(src, dst, runcnt, binned, e, nbuck);

    // layer 1: bucket-block gather (4-dim) + fused dense/projection to z (8-dim)
    k_gx2<<<nbuck, 256, 0, stream>>>(binned, boff, xs, agg4, n);
    k_hz<<<(n + 3) / 4, 256, 0, stream>>>(agg4, W1, b1, C, dinv, z, n);

    // layer 2: bucket-block gather in z-space + pooling, then log_softmax
    k_gz2<<<nbuck, 256, 0, stream>>>(binned, boff, z, dinv, batch, pool, pcnt, n);
    k_lsm<<<1, 64, 0, stream>>>(pool, pcnt, blin, bb2, out);
}

// Round 9
// 259.220 us; speedup vs baseline: 1.5062x; 1.5062x over previous
//
#include <hip/hip_runtime.h>
#include <math.h>

#define HID 128
#define NEXP 8
#define NGRAPH 64
#define EPC 16384      // edges per chunk (pass A blocks)
#define MAXB 512       // max coarse buckets (n <= 131072)
#define NREP 8         // pool replicas (atomic-contention spreading)
#define NPS 4          // nodes per slot in k_gz

__device__ inline unsigned short f2bf(float f) {
    unsigned u = __float_as_uint(f);
    u += 0x7FFF + ((u >> 16) & 1);          // RNE
    return (unsigned short)(u >> 16);
}
__device__ inline float bf2f(unsigned short u) {
    return __uint_as_float(((unsigned)u) << 16);
}

// ---------------- init: pool/pcnt/bcnt zero, C = W2@Wlin, bb2 = b2@Wlin --------
__global__ void k_init0(float* __restrict__ pool, float* __restrict__ pcnt,
                        const float* __restrict__ W2, const float* __restrict__ Wlin,
                        const float* __restrict__ b2, float* __restrict__ C,
                        float* __restrict__ bb2, int* __restrict__ bcnt) {
    int i = blockIdx.x * 256 + threadIdx.x;
    if (i < MAXB) bcnt[i] = 0;
    if (i < NREP * NGRAPH * NEXP) pool[i] = 0.0f;
    if (i < NREP * NGRAPH) pcnt[i] = 0.0f;
    int ci = i - NREP * NGRAPH * NEXP;
    if (ci >= 0 && ci < HID * NEXP) {        // C[k][j] = sum_m W2[k][m]*Wlin[m][j]
        int k = ci >> 3, j = ci & 7;
        float s = 0.0f;
        for (int m = 0; m < HID; m++) s += W2[k * HID + m] * Wlin[m * NEXP + j];
        C[ci] = s;
    }
    int bi = ci - HID * NEXP;
    if (bi >= 0 && bi < NEXP) {              // bb2[j] = sum_m b2[m]*Wlin[m][j]
        float s = 0.0f;
        for (int m = 0; m < HID; m++) s += b2[m] * Wlin[m * NEXP + bi];
        bb2[bi] = s;
    }
}

// ---------------- pass 0: per-chunk coarse histogram (+bucket totals) ----------
// runcnt layout [c][b]: coalesced across threads in k_off/k_binA.
__global__ void k_hist(const int* __restrict__ dst, int* __restrict__ runcnt,
                       int* __restrict__ bcnt, int e, int nbuck) {
    __shared__ int h[MAXB];
    int c = blockIdx.x, t = threadIdx.x;
    for (int b = t; b < nbuck; b += 256) h[b] = 0;
    __syncthreads();
    int start = c * EPC;
    int end = start + EPC < e ? start + EPC : e;
    for (int i = start + t; i < end; i += 256)
        atomicAdd(&h[dst[i] >> 8], 1);
    __syncthreads();
    for (int b = t; b < nbuck; b += 256) {
        runcnt[c * nbuck + b] = h[b];
        if (h[b]) atomicAdd(&bcnt[b], h[b]);
    }
}

// ---------------- bucket scan (<=512 buckets, 1 small block) -------------------
__global__ void k_cscan(const int* __restrict__ bcnt, int* __restrict__ boff,
                        int e, int nbuck) {
    __shared__ int s[512];
    int t = threadIdx.x;
    int v = (t < nbuck) ? bcnt[t] : 0;
    s[t] = v;
    __syncthreads();
    for (int d = 1; d < 512; d <<= 1) {
        int x = (t >= d) ? s[t - d] : 0;
        __syncthreads();
        s[t] += x;
        __syncthreads();
    }
    if (t < nbuck) boff[t] = s[t] - v;
    if (t == 0) boff[nbuck] = e;
}

// ---------------- parallel per-bucket chunk prefix (coalesced over b) ----------
__global__ void k_off(int* __restrict__ runcnt, const int* __restrict__ boff,
                      int ch, int nbuck) {
    int b = blockIdx.x * 256 + threadIdx.x;
    if (b >= nbuck) return;
    int run = boff[b];
    for (int c0 = 0; c0 < ch; c0 += 8) {
        int v[8];
#pragma unroll
        for (int j = 0; j < 8; j++)
            v[j] = (c0 + j < ch) ? runcnt[(c0 + j) * nbuck + b] : 0;
#pragma unroll
        for (int j = 0; j < 8; j++) {
            if (c0 + j < ch) runcnt[(c0 + j) * nbuck + b] = run;
            run += v[j];
        }
    }
}

// ---------------- pass A: bin edges into bucket-contiguous order ---------------
__global__ void k_binA(const int* __restrict__ src, const int* __restrict__ dst,
                       const int* __restrict__ runcnt, unsigned* __restrict__ binned,
                       int e, int nbuck) {
    __shared__ int cur[MAXB];
    int c = blockIdx.x, t = threadIdx.x;
    for (int b = t; b < nbuck; b += 256) cur[b] = runcnt[c * nbuck + b];
    __syncthreads();
    int start = c * EPC;
    int end = start + EPC < e ? start + EPC : e;
    for (int i = start + t; i < end; i += 256) {
        int d = dst[i];
        int p = atomicAdd(&cur[d >> 8], 1);
        binned[p] = ((unsigned)(d & 255) << 24) | (unsigned)src[i];
    }
}

// ---------------- pass B: per-bucket fine sort + cnt/off/dinv + xs -------------
__global__ void k_binB(const unsigned* __restrict__ binned, const int* __restrict__ boff,
                       const float* __restrict__ an, const float* __restrict__ pos,
                       int* __restrict__ cnt, int* __restrict__ off,
                       float* __restrict__ dinv, float4* __restrict__ xs,
                       int* __restrict__ eidx, int n) {
    __shared__ int h[256];
    __shared__ int sc[256];
    __shared__ int cur[256];
    int b = blockIdx.x, t = threadIdx.x;
    int s0 = boff[b], s1 = boff[b + 1];
    h[t] = 0;
    __syncthreads();
    for (int k = s0 + t; k < s1; k += 256)
        atomicAdd(&h[binned[k] >> 24], 1);
    __syncthreads();
    int v = h[t];
    sc[t] = v;
    __syncthreads();
    for (int d = 1; d < 256; d <<= 1) {
        int x = (t >= d) ? sc[t - d] : 0;
        __syncthreads();
        sc[t] += x;
        __syncthreads();
    }
    int ex = sc[t] - v;          // exclusive within bucket
    cur[t] = ex;
    int node = (b << 8) + t;
    if (node < n) {
        float di = rsqrtf((float)v + 1.0f);   // +1 = self-loop
        cnt[node]  = v;
        off[node]  = s0 + ex;
        dinv[node] = di;
        xs[node] = make_float4(an[node] * di, pos[3 * node] * di,
                               pos[3 * node + 1] * di, pos[3 * node + 2] * di);
    }
    __syncthreads();
    for (int k = s0 + t; k < s1; k += 256) {
        unsigned u = binned[k];
        int p = atomicAdd(&cur[u >> 24], 1);
        eidx[s0 + p] = (int)(u & 0xFFFFFF);
    }
}

// ---------------- layer-1 gather in 4-dim space: agg4 = xs[i] + sum xs[src] ----
__global__ void k_gx(const float4* __restrict__ xs, const int* __restrict__ eidx,
                     const int* __restrict__ off, const int* __restrict__ cnt,
                     float4* __restrict__ agg4, int n) {
    int i = blockIdx.x * 256 + threadIdx.x;
    if (i >= n) return;
    float4 a = xs[i];                       // self-loop
    int o = off[i], c = cnt[i];
    int k = 0;
    for (; k + 8 <= c; k += 8) {
        int id[8];
#pragma unroll
        for (int j = 0; j < 8; j++) id[j] = eidx[o + k + j];
        float4 vv[8];
#pragma unroll
        for (int j = 0; j < 8; j++) vv[j] = xs[id[j]];
#pragma unroll
        for (int j = 0; j < 8; j++) {
            a.x += vv[j].x; a.y += vv[j].y; a.z += vv[j].z; a.w += vv[j].w;
        }
    }
    for (; k < c; k++) {
        float4 vv = xs[eidx[o + k]];
        a.x += vv.x; a.y += vv.y; a.z += vv.z; a.w += vv.w;
    }
    agg4[i] = a;
}

// ---------------- fused layer-1 dense + z projection ---------------------------
// x1_i = relu(dinv*(agg4@W1)+b1) in wave registers; z_i = (x1_i@C)*dinv, bf16[8]
__global__ void k_hz(const float4* __restrict__ agg4, const float* __restrict__ W1,
                     const float* __restrict__ b1, const float* __restrict__ C,
                     const float* __restrict__ dinv, unsigned short* __restrict__ z,
                     int n) {
    __shared__ float xh[4][HID];
    int w = threadIdx.x >> 6;
    int i = blockIdx.x * 4 + w;
    int p = threadIdx.x & 63;
    int ic = i < n ? i : n - 1;
    const float2* W1v = (const float2*)W1;
    float2 w0 = W1v[0 * 64 + p], w1 = W1v[1 * 64 + p],
           w2 = W1v[2 * 64 + p], w3 = W1v[3 * 64 + p];
    float4 a = agg4[ic];
    float di = dinv[ic];
    float2 bb = ((const float2*)b1)[p];
    float h0 = fmaxf(di * (a.x * w0.x + a.y * w1.x + a.z * w2.x + a.w * w3.x) + bb.x, 0.0f);
    float h1 = fmaxf(di * (a.x * w0.y + a.y * w1.y + a.z * w2.y + a.w * w3.y) + bb.y, 0.0f);
    xh[w][2 * p]     = h0;
    xh[w][2 * p + 1] = h1;
    __syncthreads();
    int seg = p >> 3, j = p & 7;
    float val = 0.0f;
#pragma unroll
    for (int q = 0; q < 16; q++) {
        int c = seg * 16 + q;
        val += xh[w][c] * C[c * NEXP + j];
    }
#pragma unroll
    for (int m = 8; m < 64; m <<= 1)
        val += __shfl_xor(val, m, 64);
    if (p < 8 && i < n) z[(size_t)i * NEXP + p] = f2bf(val * di);
}

// ---------------- fused gather2 (8-dim bf16 z) + segment pooling ---------------
// wave = 8 slots x 8 comp-lanes; slot handles NPS consecutive nodes; register
// run-accumulation by graph; flush to replicated pool via atomics.
__global__ void k_gz(const unsigned short* __restrict__ z, const int* __restrict__ eidx,
                     const int* __restrict__ off, const int* __restrict__ cnt,
                     const float* __restrict__ dinv, const int* __restrict__ batch,
                     float* __restrict__ pool, float* __restrict__ pcnt, int n) {
    int t = threadIdx.x;
    int slot = t >> 3;          // 0..31 within block
    int j = t & 7;
    int i0 = blockIdx.x * (32 * NPS) + slot * NPS;
    if (i0 >= n) return;
    int i1 = i0 + NPS < n ? i0 + NPS : n;
    int rep = (blockIdx.x + slot) & (NREP - 1);
    float* rp  = pool + (size_t)rep * NGRAPH * NEXP;
    float* rpc = pcnt + (size_t)rep * NGRAPH;

    int curg = -1;
    float r = 0.0f, runlen = 0.0f;
    for (int i = i0; i < i1; i++) {
        float acc = bf2f(z[(size_t)i * NEXP + j]);   // self-loop
        int o = off[i], c = cnt[i];
        int k = 0;
        for (; k + 4 <= c; k += 4) {
            int s0 = eidx[o + k], s1 = eidx[o + k + 1];
            int s2 = eidx[o + k + 2], s3 = eidx[o + k + 3];
            unsigned short u0 = z[(size_t)s0 * NEXP + j];
            unsigned short u1 = z[(size_t)s1 * NEXP + j];
            unsigned short u2 = z[(size_t)s2 * NEXP + j];
            unsigned short u3 = z[(size_t)s3 * NEXP + j];
            acc += bf2f(u0) + bf2f(u1) + bf2f(u2) + bf2f(u3);
        }
        for (; k < c; k++)
            acc += bf2f(z[(size_t)eidx[o + k] * NEXP + j]);
        float v = dinv[i] * acc;
        int g = batch[i];
        if (g != curg) {                     // slot-uniform branch
            if (curg >= 0) {
                atomicAdd(&rp[curg * NEXP + j], r);
                if (j == 0) atomicAdd(&rpc[curg], runlen);
            }
            curg = g; r = v; runlen = 1.0f;
        } else { r += v; runlen += 1.0f; }
    }
    if (curg >= 0) {
        atomicAdd(&rp[curg * NEXP + j], r);
        if (j == 0) atomicAdd(&rpc[curg], runlen);
    }
}

// ---------------- replica-sum + mean + (blin + b2@Wlin) + log_softmax ----------
__global__ void k_lsm(const float* __restrict__ pool, const float* __restrict__ pcnt,
                      const float* __restrict__ blin, const float* __restrict__ bb2,
                      float* __restrict__ out) {
    int g = threadIdx.x;
    if (g >= NGRAPH) return;
    float p[NEXP];
#pragma unroll
    for (int k = 0; k < NEXP; k++) p[k] = 0.0f;
    float cg = 0.0f;
#pragma unroll
    for (int rr = 0; rr < NREP; rr++) {
#pragma unroll
        for (int k = 0; k < NEXP; k++) p[k] += pool[rr * NGRAPH * NEXP + g * NEXP + k];
        cg += pcnt[rr * NGRAPH + g];
    }
    float inv = 1.0f / fmaxf(cg, 1.0f);
    float v[NEXP], m = -1e30f;
#pragma unroll
    for (int k = 0; k < NEXP; k++) {
        v[k] = p[k] * inv + blin[k] + bb2[k];
        m = fmaxf(m, v[k]);
    }
    float s = 0.0f;
#pragma unroll
    for (int k = 0; k < NEXP; k++) s += expf(v[k] - m);
    float ls = logf(s);
#pragma unroll
    for (int k = 0; k < NEXP; k++) out[g * NEXP + k] = v[k] - m - ls;
}

extern "C" void kernel_launch(void* const* d_in, const int* in_sizes, int n_in,
                              void* d_out, int out_size, void* d_ws, size_t ws_size,
                              hipStream_t stream) {
    const float* an   = (const float*)d_in[0];
    const float* pos  = (const float*)d_in[1];
    const int*   ei   = (const int*)d_in[2];     // [2, E] flat (int32 view)
    const int*   batch= (const int*)d_in[3];
    const float* W1   = (const float*)d_in[4];
    const float* b1   = (const float*)d_in[5];
    const float* W2   = (const float*)d_in[6];
    const float* b2   = (const float*)d_in[7];
    const float* Wlin = (const float*)d_in[8];
    const float* blin = (const float*)d_in[9];
    float* out = (float*)d_out;

    const int n = in_sizes[0];
    const int e = in_sizes[2] / 2;
    const int* src = ei;
    const int* dst = ei + e;

    const int nbuck = (n + 255) >> 8;            // coarse buckets (<= MAXB)
    const int ch    = (e + EPC - 1) / EPC;       // chunks

    // workspace layout (16B-aligned buffers first)
    char* p = (char*)d_ws;
    float4* xs    = (float4*)p;       p += sizeof(float4) * (size_t)n;
    float4* agg4  = (float4*)p;       p += sizeof(float4) * (size_t)n;
    unsigned short* z = (unsigned short*)p;  p += sizeof(short) * (size_t)n * NEXP;
    float* C      = (float*)p;        p += sizeof(float) * HID * NEXP;
    float* bb2    = (float*)p;        p += sizeof(float) * NEXP;
    float* dinv   = (float*)p;        p += sizeof(float) * (size_t)n;
    float* pool   = (float*)p;        p += sizeof(float) * NREP * NGRAPH * NEXP;
    float* pcnt   = (float*)p;        p += sizeof(float) * NREP * NGRAPH;
    int*   cnt    = (int*)p;          p += sizeof(int) * (size_t)n;
    int*   off    = (int*)p;          p += sizeof(int) * (size_t)n;
    int*   bcnt   = (int*)p;          p += sizeof(int) * (MAXB + 1);
    int*   boff   = (int*)p;          p += sizeof(int) * (MAXB + 1);
    int*   runcnt = (int*)p;          p += sizeof(int) * (size_t)ch * nbuck;
    unsigned* binned = (unsigned*)p;  p += sizeof(unsigned) * (size_t)e;
    int*   eidx   = (int*)p;          p += sizeof(int) * (size_t)e;

    // init + CSR build via two-phase counting sort (parallel scan stages)
    const int initN = NREP * NGRAPH * NEXP + HID * NEXP + NEXP;
    k_init0<<<(initN + 255) / 256, 256, 0, stream>>>(pool, pcnt, W2, Wlin, b2, C, bb2, bcnt);
    k_hist<<<ch, 256, 0, stream>>>(dst, runcnt, bcnt, e, nbuck);
    k_cscan<<<1, 512, 0, stream>>>(bcnt, boff, e, nbuck);
    k_off<<<(nbuck + 255) / 256, 256, 0, stream>>>(runcnt, boff, ch, nbuck);
    k_binA<<<ch, 256, 0, stream>>>(src, dst, runcnt, binned, e, nbuck);
    k_binB<<<nbuck, 256, 0, stream>>>(binned, boff, an, pos, cnt, off, dinv, xs, eidx, n);

    // layer 1 gather (4-dim) + fused dense/projection to z (8-dim)
    k_gx<<<(n + 255) / 256, 256, 0, stream>>>(xs, eidx, off, cnt, agg4, n);
    k_hz<<<(n + 3) / 4, 256, 0, stream>>>(agg4, W1, b1, C, dinv, z, n);

    // layer 2 gather in 8-dim z-space + pooling, then log_softmax
    k_gz<<<(n + 32 * NPS - 1) / (32 * NPS), 256, 0, stream>>>(z, eidx, off, cnt,
                                                              dinv, batch, pool, pcnt, n);
    k_lsm<<<1, 64, 0, stream>>>(pool, pcnt, blin, bb2, out);
}

// Round 10
// 256.797 us; speedup vs baseline: 1.5204x; 1.0094x over previous
//
#include <hip/hip_runtime.h>
#include <math.h>

#define HID 128
#define NEXP 8
#define NGRAPH 64
#define EPC 2048       // edges per chunk (hist/binA blocks) - small for occupancy
#define MAXB 512       // max coarse buckets (n <= 131072)
#define NREP 8         // pool replicas (atomic-contention spreading)
#define NPS 4          // nodes per slot in k_gz

__device__ inline unsigned short f2bf(float f) {
    unsigned u = __float_as_uint(f);
    u += 0x7FFF + ((u >> 16) & 1);          // RNE
    return (unsigned short)(u >> 16);
}
__device__ inline float bf2f(unsigned short u) {
    return __uint_as_float(((unsigned)u) << 16);
}

// ---------------- init: pool/pcnt/bcnt zero, C = W2@Wlin, bb2 = b2@Wlin --------
__global__ void k_init0(float* __restrict__ pool, float* __restrict__ pcnt,
                        const float* __restrict__ W2, const float* __restrict__ Wlin,
                        const float* __restrict__ b2, float* __restrict__ C,
                        float* __restrict__ bb2, int* __restrict__ bcnt) {
    int i = blockIdx.x * 256 + threadIdx.x;
    if (i < MAXB) bcnt[i] = 0;
    if (i < NREP * NGRAPH * NEXP) pool[i] = 0.0f;
    if (i < NREP * NGRAPH) pcnt[i] = 0.0f;
    int ci = i - NREP * NGRAPH * NEXP;
    if (ci >= 0 && ci < HID * NEXP) {        // C[k][j] = sum_m W2[k][m]*Wlin[m][j]
        int k = ci >> 3, j = ci & 7;
        float s = 0.0f;
        for (int m = 0; m < HID; m++) s += W2[k * HID + m] * Wlin[m * NEXP + j];
        C[ci] = s;
    }
    int bi = ci - HID * NEXP;
    if (bi >= 0 && bi < NEXP) {              // bb2[j] = sum_m b2[m]*Wlin[m][j]
        float s = 0.0f;
        for (int m = 0; m < HID; m++) s += b2[m] * Wlin[m * NEXP + bi];
        bb2[bi] = s;
    }
}

// ---------------- pass 0: coarse bucket totals only ----------------------------
__global__ void k_hist(const int* __restrict__ dst, int* __restrict__ bcnt,
                       int e, int nbuck) {
    __shared__ int h[MAXB];
    int c = blockIdx.x, t = threadIdx.x;
    for (int b = t; b < nbuck; b += 256) h[b] = 0;
    __syncthreads();
    int start = c * EPC;
    int end = start + EPC < e ? start + EPC : e;
    for (int i = start + t; i < end; i += 256)
        atomicAdd(&h[dst[i] >> 8], 1);
    __syncthreads();
    for (int b = t; b < nbuck; b += 256)
        if (h[b]) atomicAdd(&bcnt[b], h[b]);
}

// ---------------- bucket scan + cursor init (<=512 buckets, 1 block) -----------
__global__ void k_cscan(const int* __restrict__ bcnt, int* __restrict__ boff,
                        int* __restrict__ gcur, int e, int nbuck) {
    __shared__ int s[512];
    int t = threadIdx.x;
    int v = (t < nbuck) ? bcnt[t] : 0;
    s[t] = v;
    __syncthreads();
    for (int d = 1; d < 512; d <<= 1) {
        int x = (t >= d) ? s[t - d] : 0;
        __syncthreads();
        s[t] += x;
        __syncthreads();
    }
    if (t < nbuck) {
        int ex = s[t] - v;
        boff[t] = ex;
        gcur[t] = ex;
    }
    if (t == 0) boff[nbuck] = e;
}

// ---------------- pass A: dynamic-reservation binning --------------------------
// order within a bucket is arbitrary (binB fine-sorts), so each chunk reserves
// its per-bucket ranges via global cursor atomics - no runcnt pre-scan needed.
__global__ void k_binA(const int* __restrict__ src, const int* __restrict__ dst,
                       int* __restrict__ gcur, unsigned* __restrict__ binned,
                       int e, int nbuck) {
    __shared__ int h[MAXB];
    __shared__ int cur[MAXB];
    int c = blockIdx.x, t = threadIdx.x;
    for (int b = t; b < nbuck; b += 256) h[b] = 0;
    __syncthreads();
    int start = c * EPC;
    int end = start + EPC < e ? start + EPC : e;
    for (int i = start + t; i < end; i += 256)
        atomicAdd(&h[dst[i] >> 8], 1);
    __syncthreads();
    for (int b = t; b < nbuck; b += 256)
        cur[b] = h[b] ? atomicAdd(&gcur[b], h[b]) : 0;
    __syncthreads();
    for (int i = start + t; i < end; i += 256) {
        int d = dst[i];
        int p = atomicAdd(&cur[d >> 8], 1);
        binned[p] = ((unsigned)(d & 255) << 24) | (unsigned)src[i];
    }
}

// ---------------- pass B: per-bucket fine sort + cnt/off/dinv + xs -------------
__global__ void k_binB(const unsigned* __restrict__ binned, const int* __restrict__ boff,
                       const float* __restrict__ an, const float* __restrict__ pos,
                       int* __restrict__ cnt, int* __restrict__ off,
                       float* __restrict__ dinv, float4* __restrict__ xs,
                       int* __restrict__ eidx, int n) {
    __shared__ int h[256];
    __shared__ int sc[256];
    __shared__ int cur[256];
    int b = blockIdx.x, t = threadIdx.x;
    int s0 = boff[b], s1 = boff[b + 1];
    h[t] = 0;
    __syncthreads();
    for (int k = s0 + t; k < s1; k += 256)
        atomicAdd(&h[binned[k] >> 24], 1);
    __syncthreads();
    int v = h[t];
    sc[t] = v;
    __syncthreads();
    for (int d = 1; d < 256; d <<= 1) {
        int x = (t >= d) ? sc[t - d] : 0;
        __syncthreads();
        sc[t] += x;
        __syncthreads();
    }
    int ex = sc[t] - v;          // exclusive within bucket
    cur[t] = ex;
    int node = (b << 8) + t;
    if (node < n) {
        float di = rsqrtf((float)v + 1.0f);   // +1 = self-loop
        cnt[node]  = v;
        off[node]  = s0 + ex;
        dinv[node] = di;
        xs[node] = make_float4(an[node] * di, pos[3 * node] * di,
                               pos[3 * node + 1] * di, pos[3 * node + 2] * di);
    }
    __syncthreads();
    for (int k = s0 + t; k < s1; k += 256) {
        unsigned u = binned[k];
        int p = atomicAdd(&cur[u >> 24], 1);
        eidx[s0 + p] = (int)(u & 0xFFFFFF);
    }
}

// ---------------- layer-1 gather in 4-dim space: agg4 = xs[i] + sum xs[src] ----
__global__ void k_gx(const float4* __restrict__ xs, const int* __restrict__ eidx,
                     const int* __restrict__ off, const int* __restrict__ cnt,
                     float4* __restrict__ agg4, int n) {
    int i = blockIdx.x * 256 + threadIdx.x;
    if (i >= n) return;
    float4 a = xs[i];                       // self-loop
    int o = off[i], c = cnt[i];
    int k = 0;
    for (; k + 8 <= c; k += 8) {
        int id[8];
#pragma unroll
        for (int j = 0; j < 8; j++) id[j] = eidx[o + k + j];
        float4 vv[8];
#pragma unroll
        for (int j = 0; j < 8; j++) vv[j] = xs[id[j]];
#pragma unroll
        for (int j = 0; j < 8; j++) {
            a.x += vv[j].x; a.y += vv[j].y; a.z += vv[j].z; a.w += vv[j].w;
        }
    }
    for (; k < c; k++) {
        float4 vv = xs[eidx[o + k]];
        a.x += vv.x; a.y += vv.y; a.z += vv.z; a.w += vv.w;
    }
    agg4[i] = a;
}

// ---------------- fused layer-1 dense + z projection ---------------------------
// x1_i = relu(dinv*(agg4@W1)+b1) in wave registers; z_i = (x1_i@C)*dinv, bf16[8]
__global__ void k_hz(const float4* __restrict__ agg4, const float* __restrict__ W1,
                     const float* __restrict__ b1, const float* __restrict__ C,
                     const float* __restrict__ dinv, unsigned short* __restrict__ z,
                     int n) {
    __shared__ float xh[4][HID];
    int w = threadIdx.x >> 6;
    int i = blockIdx.x * 4 + w;
    int p = threadIdx.x & 63;
    int ic = i < n ? i : n - 1;
    const float2* W1v = (const float2*)W1;
    float2 w0 = W1v[0 * 64 + p], w1 = W1v[1 * 64 + p],
           w2 = W1v[2 * 64 + p], w3 = W1v[3 * 64 + p];
    float4 a = agg4[ic];
    float di = dinv[ic];
    float2 bb = ((const float2*)b1)[p];
    float h0 = fmaxf(di * (a.x * w0.x + a.y * w1.x + a.z * w2.x + a.w * w3.x) + bb.x, 0.0f);
    float h1 = fmaxf(di * (a.x * w0.y + a.y * w1.y + a.z * w2.y + a.w * w3.y) + bb.y, 0.0f);
    xh[w][2 * p]     = h0;
    xh[w][2 * p + 1] = h1;
    __syncthreads();
    int seg = p >> 3, j = p & 7;
    float val = 0.0f;
#pragma unroll
    for (int q = 0; q < 16; q++) {
        int c = seg * 16 + q;
        val += xh[w][c] * C[c * NEXP + j];
    }
#pragma unroll
    for (int m = 8; m < 64; m <<= 1)
        val += __shfl_xor(val, m, 64);
    if (p < 8 && i < n) z[(size_t)i * NEXP + p] = f2bf(val * di);
}

// ---------------- fused gather2 (8-dim bf16 z) + segment pooling ---------------
// wave = 8 slots x 8 comp-lanes; slot handles NPS consecutive nodes; register
// run-accumulation by graph; flush to replicated pool via atomics.
__global__ void k_gz(const unsigned short* __restrict__ z, const int* __restrict__ eidx,
                     const int* __restrict__ off, const int* __restrict__ cnt,
                     const float* __restrict__ dinv, const int* __restrict__ batch,
                     float* __restrict__ pool, float* __restrict__ pcnt, int n) {
    int t = threadIdx.x;
    int slot = t >> 3;          // 0..31 within block
    int j = t & 7;
    int i0 = blockIdx.x * (32 * NPS) + slot * NPS;
    if (i0 >= n) return;
    int i1 = i0 + NPS < n ? i0 + NPS : n;
    int rep = (blockIdx.x + slot) & (NREP - 1);
    float* rp  = pool + (size_t)rep * NGRAPH * NEXP;
    float* rpc = pcnt + (size_t)rep * NGRAPH;

    int curg = -1;
    float r = 0.0f, runlen = 0.0f;
    for (int i = i0; i < i1; i++) {
        float acc = bf2f(z[(size_t)i * NEXP + j]);   // self-loop
        int o = off[i], c = cnt[i];
        int k = 0;
        for (; k + 4 <= c; k += 4) {
            int s0 = eidx[o + k], s1 = eidx[o + k + 1];
            int s2 = eidx[o + k + 2], s3 = eidx[o + k + 3];
            unsigned short u0 = z[(size_t)s0 * NEXP + j];
            unsigned short u1 = z[(size_t)s1 * NEXP + j];
            unsigned short u2 = z[(size_t)s2 * NEXP + j];
            unsigned short u3 = z[(size_t)s3 * NEXP + j];
            acc += bf2f(u0) + bf2f(u1) + bf2f(u2) + bf2f(u3);
        }
        for (; k < c; k++)
            acc += bf2f(z[(size_t)eidx[o + k] * NEXP + j]);
        float v = dinv[i] * acc;
        int g = batch[i];
        if (g != curg) {                     // slot-uniform branch
            if (curg >= 0) {
                atomicAdd(&rp[curg * NEXP + j], r);
                if (j == 0) atomicAdd(&rpc[curg], runlen);
            }
            curg = g; r = v; runlen = 1.0f;
        } else { r += v; runlen += 1.0f; }
    }
    if (curg >= 0) {
        atomicAdd(&rp[curg * NEXP + j], r);
        if (j == 0) atomicAdd(&rpc[curg], runlen);
    }
}

// ---------------- replica-sum + mean + (blin + b2@Wlin) + log_softmax ----------
__global__ void k_lsm(const float* __restrict__ pool, const float* __restrict__ pcnt,
                      const float* __restrict__ blin, const float* __restrict__ bb2,
                      float* __restrict__ out) {
    int g = threadIdx.x;
    if (g >= NGRAPH) return;
    float p[NEXP];
#pragma unroll
    for (int k = 0; k < NEXP; k++) p[k] = 0.0f;
    float cg = 0.0f;
#pragma unroll
    for (int rr = 0; rr < NREP; rr++) {
#pragma unroll
        for (int k = 0; k < NEXP; k++) p[k] += pool[rr * NGRAPH * NEXP + g * NEXP + k];
        cg += pcnt[rr * NGRAPH + g];
    }
    float inv = 1.0f / fmaxf(cg, 1.0f);
    float v[NEXP], m = -1e30f;
#pragma unroll
    for (int k = 0; k < NEXP; k++) {
        v[k] = p[k] * inv + blin[k] + bb2[k];
        m = fmaxf(m, v[k]);
    }
    float s = 0.0f;
#pragma unroll
    for (int k = 0; k < NEXP; k++) s += expf(v[k] - m);
    float ls = logf(s);
#pragma unroll
    for (int k = 0; k < NEXP; k++) out[g * NEXP + k] = v[k] - m - ls;
}

extern "C" void kernel_launch(void* const* d_in, const int* in_sizes, int n_in,
                              void* d_out, int out_size, void* d_ws, size_t ws_size,
                              hipStream_t stream) {
    const float* an   = (const float*)d_in[0];
    const float* pos  = (const float*)d_in[1];
    const int*   ei   = (const int*)d_in[2];     // [2, E] flat (int32 view)
    const int*   batch= (const int*)d_in[3];
    const float* W1   = (const float*)d_in[4];
    const float* b1   = (const float*)d_in[5];
    const float* W2   = (const float*)d_in[6];
    const float* b2   = (const float*)d_in[7];
    const float* Wlin = (const float*)d_in[8];
    const float* blin = (const float*)d_in[9];
    float* out = (float*)d_out;

    const int n = in_sizes[0];
    const int e = in_sizes[2] / 2;
    const int* src = ei;
    const int* dst = ei + e;

    const int nbuck = (n + 255) >> 8;            // coarse buckets (<= MAXB)
    const int ch    = (e + EPC - 1) / EPC;       // chunks

    // workspace layout (16B-aligned buffers first)
    char* p = (char*)d_ws;
    float4* xs    = (float4*)p;       p += sizeof(float4) * (size_t)n;
    float4* agg4  = (float4*)p;       p += sizeof(float4) * (size_t)n;
    unsigned short* z = (unsigned short*)p;  p += sizeof(short) * (size_t)n * NEXP;
    float* C      = (float*)p;        p += sizeof(float) * HID * NEXP;
    float* bb2    = (float*)p;        p += sizeof(float) * NEXP;
    float* dinv   = (float*)p;        p += sizeof(float) * (size_t)n;
    float* pool   = (float*)p;        p += sizeof(float) * NREP * NGRAPH * NEXP;
    float* pcnt   = (float*)p;        p += sizeof(float) * NREP * NGRAPH;
    int*   cnt    = (int*)p;          p += sizeof(int) * (size_t)n;
    int*   off    = (int*)p;          p += sizeof(int) * (size_t)n;
    int*   bcnt   = (int*)p;          p += sizeof(int) * (MAXB + 1);
    int*   boff   = (int*)p;          p += sizeof(int) * (MAXB + 1);
    int*   gcur   = (int*)p;          p += sizeof(int) * (MAXB + 1);
    unsigned* binned = (unsigned*)p;  p += sizeof(unsigned) * (size_t)e;
    int*   eidx   = (int*)p;          p += sizeof(int) * (size_t)e;

    // init + CSR build via dynamic-reservation counting sort
    const int initN = NREP * NGRAPH * NEXP + HID * NEXP + NEXP;
    k_init0<<<(initN + 255) / 256, 256, 0, stream>>>(pool, pcnt, W2, Wlin, b2, C, bb2, bcnt);
    k_hist<<<ch, 256, 0, stream>>>(dst, bcnt, e, nbuck);
    k_cscan<<<1, 512, 0, stream>>>(bcnt, boff, gcur, e, nbuck);
    k_binA<<<ch, 256, 0, stream>>>(src, dst, gcur, binned, e, nbuck);
    k_binB<<<nbuck, 256, 0, stream>>>(binned, boff, an, pos, cnt, off, dinv, xs, eidx, n);

    // layer 1 gather (4-dim) + fused dense/projection to z (8-dim)
    k_gx<<<(n + 255) / 256, 256, 0, stream>>>(xs, eidx, off, cnt, agg4, n);
    k_hz<<<(n + 3) / 4, 256, 0, stream>>>(agg4, W1, b1, C, dinv, z, n);

    // layer 2 gather in 8-dim z-space + pooling, then log_softmax
    k_gz<<<(n + 32 * NPS - 1) / (32 * NPS), 256, 0, stream>>>(z, eidx, off, cnt,
                                                              dinv, batch, pool, pcnt, n);
    k_lsm<<<1, 64, 0, stream>>>(pool, pcnt, blin, bb2, out);
}